// Round 10
// baseline (54.938 us; speedup 1.0000x reference)
//
#include <hip/hip_runtime.h>
#include <cstddef>

#define NB 8
#define NN 1024
#define NF 32
#define NIDX 4
#define JC 4            // j-chunks per pass (grid z)
#define JCH 256         // j's per chunk
#define NJT 4           // 64-wide j-tiles per chunk
#define TIB 32          // i-rows per block (4 waves x 8)

// ---- ws layout (float offsets) ----
#define OFF_ROW   0u
#define OFF_COLP  8192u          // [64][8192]
#define OFF_DINV  532480u
#define OFF_P     540672u        // [8192][8]
#define OFF_R     606208u
#define OFF_WT    671744u        // [65536] wtot
#define OFF_WP    737280u        // [JC][65536]

#if __has_builtin(__builtin_amdgcn_sinf)
#define FSIN(x) __builtin_amdgcn_sinf(x)   // sin(2*pi*x), |x|<0.5 here
#define FCOS(x) __builtin_amdgcn_cosf(x)
#else
#define FSIN(x) __sinf((x) * 6.283185307179586f)
#define FCOS(x) __cosf((x) * 6.283185307179586f)
#endif

// Fused row+col sums of adj in one read. grid (NB,64): bid%8==b -> XCD b gets adj[b].
__global__ __launch_bounds__(512) void k_sums(const float* __restrict__ adj,
                                              float* __restrict__ rowsum,
                                              float* __restrict__ colpart) {
  int b = blockIdx.x, strip = blockIdx.y;
  int t = threadIdx.x, lane = t & 63, w = t >> 6;
  float colreg[16];
  #pragma unroll
  for (int i = 0; i < 16; ++i) colreg[i] = 0.f;
  int r0 = strip*16 + w*2;
  #pragma unroll
  for (int rr = 0; rr < 2; ++rr) {
    const float4* row4 = reinterpret_cast<const float4*>(adj + ((size_t)b*NN + r0 + rr)*NN);
    float rs = 0.f;
    #pragma unroll
    for (int cq = 0; cq < 4; ++cq) {
      float4 v = row4[cq*64 + lane];
      colreg[cq*4+0] += v.x; colreg[cq*4+1] += v.y;
      colreg[cq*4+2] += v.z; colreg[cq*4+3] += v.w;
      rs += (v.x + v.y) + (v.z + v.w);
    }
    #pragma unroll
    for (int o = 32; o > 0; o >>= 1) rs += __shfl_xor(rs, o);
    if (lane == 0) rowsum[b*NN + r0 + rr] = rs;
  }
  __shared__ float cacc[8][NN];
  #pragma unroll
  for (int cq = 0; cq < 4; ++cq)
    #pragma unroll
    for (int x = 0; x < 4; ++x) cacc[w][cq*256 + lane*4 + x] = colreg[cq*4+x];
  __syncthreads();
  for (int c = t; c < NN; c += 512) {
    float s = 0.f;
    #pragma unroll
    for (int ww = 0; ww < 8; ++ww) s += cacc[ww][c];
    colpart[(size_t)strip*(NB*NN) + b*NN + c] = s;
  }
}

// dinv + feature contractions; pre-initializes out = s + bias.
// p=(w1+2w2).X, r=dinv*(-2w2).X, out=(w0+w2).X + bias
__global__ __launch_bounds__(256) void k_prep(const float* __restrict__ Xr, const float* __restrict__ Xi,
                       const float* __restrict__ weight,
                       const float* __restrict__ rowsum, const float* __restrict__ colpart,
                       const float* __restrict__ bias,
                       float* __restrict__ dinv,
                       float* __restrict__ pvec, float* __restrict__ rvec,
                       float* __restrict__ out) {
  __shared__ float wsm[NIDX*3*NF];
  int t = threadIdx.x;
  for (int e = t; e < NIDX*3*NF; e += 256) wsm[e] = weight[e];
  __syncthreads();
  int gid = blockIdx.x*256 + t;
  float cs = 0.f;
  for (int k = 0; k < 64; ++k) cs += colpart[(size_t)k*(NB*NN) + gid];
  float D = 0.5f*(rowsum[gid] + cs);
  float di = (D > 0.f) ? (1.0f / sqrtf(D)) : 0.f;
  dinv[gid] = di;
  const float* xr = Xr + (size_t)gid*NF;
  const float* xi = Xi + (size_t)gid*NF;
  float acc[NIDX][3][2];
  #pragma unroll
  for (int x = 0; x < NIDX; ++x)
    #pragma unroll
    for (int v = 0; v < 3; ++v) { acc[x][v][0] = 0.f; acc[x][v][1] = 0.f; }
  for (int f = 0; f < NF; ++f) {
    float xrf = xr[f], xif = xi[f];
    #pragma unroll
    for (int x = 0; x < NIDX; ++x) {
      float w0 = wsm[x*96 + f], w1 = wsm[x*96 + 32 + f], w2 = wsm[x*96 + 64 + f];
      float av = w0 + w2, bv = w1 + 2.f*w2, cv = -2.f*w2;
      acc[x][0][0] += av*xrf; acc[x][0][1] += av*xif;
      acc[x][1][0] += bv*xrf; acc[x][1][1] += bv*xif;
      acc[x][2][0] += cv*xrf; acc[x][2][1] += cv*xif;
    }
  }
  #pragma unroll
  for (int x = 0; x < NIDX; ++x) {
    size_t o = (size_t)gid*8 + x*2;
    pvec[o] = acc[x][1][0];      pvec[o+1] = acc[x][1][1];
    rvec[o] = di*acc[x][2][0];   rvec[o+1] = di*acc[x][2][1];
    out[gid*4 + x]         = acc[x][0][0] + bias[x];   // real
    out[32768 + gid*4 + x] = acc[x][0][1];             // imag
  }
}

// wtot = dinv * (pvec + sum_c wpart[c])
__global__ void k_mid(const float* __restrict__ dinv, const float* __restrict__ pvec,
                      const float* __restrict__ wpart, float* __restrict__ wtot) {
  int o = blockIdx.x*256 + threadIdx.x;   // 65536
  float v = pvec[o];
  #pragma unroll
  for (int c = 0; c < JC; ++c) v += wpart[(size_t)c*65536 + o];
  wtot[o] = v * dinv[o >> 3];
}

// Barrier-free, LDS-free M-application. Block = 4 waves; wave owns 8 i-rows,
// lanes on j. ac[s]=adj[j][ibase+s] = 2 per-lane float4 (4KB stride, L2);
// ar = coalesced row stream. vin has dinv_j prefolded. grid (NB, 32, JC).
// MODE 0: plain-store partials to outp[zc]. MODE 1: atomicAdd into out.
template<int MODE>
__global__ __launch_bounds__(256, 4) void k_pass(const float* __restrict__ adj,
                                                 const float* __restrict__ dinv,
                                                 const float* __restrict__ vin,
                                                 float* __restrict__ outp) {
  __shared__ float red[4][8*72];
  int b = blockIdx.x, i0 = blockIdx.y*TIB, zc = blockIdx.z;
  int t = threadIdx.x, lane = t & 63, w = t >> 6;
  int wu = __builtin_amdgcn_readfirstlane(w);
  int ibase = i0 + wu*8;
  float accr[8][NIDX], acci[8][NIDX];
  #pragma unroll
  for (int s = 0; s < 8; ++s)
    #pragma unroll
    for (int x = 0; x < NIDX; ++x) { accr[s][x] = 0.f; acci[s][x] = 0.f; }

  for (int jt = 0; jt < NJT; ++jt) {
    int j0 = zc*JCH + jt*64;
    int jg = j0 + lane;
    const float4* acp = reinterpret_cast<const float4*>(adj + ((size_t)b*NN + jg)*NN + ibase);
    float4 ac0 = acp[0], ac1 = acp[1];                  // adj[j][ibase..+8]
    const float4* vp = reinterpret_cast<const float4*>(vin + ((size_t)b*NN + jg)*8);
    float4 v0 = vp[0], v1 = vp[1];
    float vr[NIDX] = {v0.x, v0.z, v1.x, v1.z};
    float vi[NIDX] = {v0.y, v0.w, v1.y, v1.w};
    float acv[8] = {ac0.x, ac0.y, ac0.z, ac0.w, ac1.x, ac1.y, ac1.z, ac1.w};
    const float* arb = adj + ((size_t)b*NN + ibase)*NN + j0 + lane;
    #pragma unroll
    for (int s = 0; s < 8; ++s) {
      float ar = arb[(size_t)s*NN];                     // adj[i][j], coalesced
      float ac = acv[s];
      float dd = ar - ac, sm = ar + ac;
      float s4 = FSIN(0.25f*dd), c4 = FCOS(0.25f*dd);   // q=1/4 seed
      float s3 = FSIN((1.f/3.f)*dd), c3 = FCOS((1.f/3.f)*dd);
      float s5 = FSIN(0.2f*dd), c5 = FCOS(0.2f*dd);
      float c2 = 1.f - 2.f*s4*s4, s2 = 2.f*s4*c4;       // q=1/2 exact double-angle
      float csv[NIDX] = {c2, c3, c4, c5};
      float snv[NIDX] = {s2, s3, s4, s5};
      #pragma unroll
      for (int x = 0; x < NIDX; ++x) {
        float A = sm*csv[x], B = sm*snv[x];
        accr[s][x] += A*vr[x] - B*vi[x];
        acci[s][x] += A*vi[x] + B*vr[x];
      }
    }
  }

  // in-wave 8x8 transpose-reduce (R4-verified): lane ends with slot (lane&7)
  // of i-step s summed over its 8-lane group.
  bool b1 = (lane & 1), b2 = (lane & 2), b4 = (lane & 4);
  #pragma unroll
  for (int s = 0; s < 8; ++s) {
    float v0 = accr[s][0], v1 = acci[s][0], v2 = accr[s][1], v3 = acci[s][1];
    float v4 = accr[s][2], v5 = acci[s][2], v6 = accr[s][3], v7 = acci[s][3];
    float k0 = b1 ? v1 : v0, s0 = b1 ? v0 : v1;
    float k1 = b1 ? v3 : v2, s1 = b1 ? v2 : v3;
    float k2 = b1 ? v5 : v4, s2 = b1 ? v4 : v5;
    float k3 = b1 ? v7 : v6, s3 = b1 ? v6 : v7;
    v0 = k0 + __shfl_xor(s0, 1);
    v1 = k1 + __shfl_xor(s1, 1);
    v2 = k2 + __shfl_xor(s2, 1);
    v3 = k3 + __shfl_xor(s3, 1);
    k0 = b2 ? v1 : v0; s0 = b2 ? v0 : v1;
    k1 = b2 ? v3 : v2; s1 = b2 ? v2 : v3;
    v0 = k0 + __shfl_xor(s0, 2);
    v1 = k1 + __shfl_xor(s1, 2);
    k0 = b4 ? v1 : v0; s0 = b4 ? v0 : v1;
    v0 = k0 + __shfl_xor(s0, 4);
    red[w][s*72 + (lane & 7)*9 + (lane >> 3)] = v0;
  }
  __syncthreads();
  {
    int row = lane >> 3, slot = lane & 7;    // wave-local: 8 rows x 8 slots
    float sum = 0.f;
    #pragma unroll
    for (int g = 0; g < 8; ++g) sum += red[w][row*72 + slot*9 + g];
    int gi = b*NN + ibase + row;
    float val = sum * 0.5f * dinv[gi];
    if constexpr (MODE == 0) outp[(size_t)zc*65536 + (size_t)gi*8 + slot] = val;
    else atomicAdd(&outp[(slot & 1)*32768 + gi*4 + (slot >> 1)], val);
  }
}

extern "C" void kernel_launch(void* const* d_in, const int* in_sizes, int n_in,
                              void* d_out, int out_size, void* d_ws, size_t ws_size,
                              hipStream_t stream) {
  (void)in_sizes; (void)n_in; (void)out_size; (void)ws_size;
  const float* Xr     = (const float*)d_in[0];
  const float* Xi     = (const float*)d_in[1];
  const float* adj    = (const float*)d_in[2];
  const float* weight = (const float*)d_in[3];
  const float* bias   = (const float*)d_in[4];
  float* ws = (float*)d_ws;
  float* rowsum  = ws + OFF_ROW;
  float* colpart = ws + OFF_COLP;
  float* dinv    = ws + OFF_DINV;
  float* pvec    = ws + OFF_P;
  float* rvec    = ws + OFF_R;
  float* wtot    = ws + OFF_WT;
  float* wpart   = ws + OFF_WP;
  float* out = (float*)d_out;

  k_sums<<<dim3(NB, 64), 512, 0, stream>>>(adj, rowsum, colpart);
  k_prep<<<dim3(NB*NN/256), 256, 0, stream>>>(Xr, Xi, weight, rowsum, colpart, bias,
                                              dinv, pvec, rvec, out);
  k_pass<0><<<dim3(NB, NN/TIB, JC), 256, 0, stream>>>(adj, dinv, rvec, wpart);
  k_mid<<<dim3(256), 256, 0, stream>>>(dinv, pvec, wpart, wtot);
  k_pass<1><<<dim3(NB, NN/TIB, JC), 256, 0, stream>>>(adj, dinv, wtot, out);
}